// Round 15
// baseline (75.804 us; speedup 1.0000x reference)
//
#include <hip/hip_runtime.h>
#include <math.h>
#include <stdint.h>

#define KK 5
#define PADK 2
#define C_IN 8
#define O_OUT 8
#define HH 512
#define WW 512
#define TH 8
#define TW 128
#define CH 4                      // channels per staged half
#define LROWS 12                  // TH + 4
#define LCOLS 136                 // TW + 4 halo, padded (f32 cols)
#define WSTR 12                   // dwords per (c,og,dy) chunk: 10 used
#define NW (O_OUT * C_IN * KK * KK)   // 1600
#define XHALF (CH * LROWS * (LCOLS / 2))   // float2 slots per half = 3264
#define NSTG 7                    // ceil(XHALF / 512)

// Full-rate VOP3 3-input max.
static __device__ __forceinline__ float max3f(float a, float b, float c) {
    float d;
    asm("v_max3_f32 %0, %1, %2, %3" : "=v"(d) : "v"(a), "v"(b), "v"(c));
    return d;
}

__global__ __launch_bounds__(512, 8)
void dil_kernel(const float* __restrict__ x,
                const float* __restrict__ wf,
                float* __restrict__ out) {
    __shared__ __align__(16) float xlds[CH][LROWS][LCOLS];      // 26,112 B
    __shared__ __align__(16) float wlds[C_IN * 4 * KK * WSTR];  //  7,680 B

    const int tid = threadIdx.x;
    const int w0 = blockIdx.x * TW;
    const int h0 = blockIdx.y * TH;
    const int n  = blockIdx.z;
    const float* xn = x + (size_t)n * (C_IN * HH * WW);

    // wave -> (o-pair og, row-quad rq); lane -> 2-pixel column strip
    const int l   = tid & 63;
    const int wid = tid >> 6;
    const int og  = wid & 3;
    const int rbase = (wid >> 2) * 4;

    // ---- T14 async staging: issue loads early (regs), write late ----
    float2 stg[NSTG];

    auto stageL = [&](int h) {          // issue 7 clamped global loads
        #pragma unroll
        for (int k = 0; k < NSTG; ++k) {
            int idx = tid + k * 512;
            if (idx < XHALF) {
                int cc  = idx / (LROWS * (LCOLS / 2));
                int rem = idx - cc * (LROWS * (LCOLS / 2));
                int r   = rem / (LCOLS / 2);
                int jp  = rem - r * (LCOLS / 2);
                int gh = h0 - PADK + r;
                int gw = w0 - PADK + 2 * jp;
                int ghc = min(max(gh, 0), HH - 1);
                int gwc = min(max(gw, 0), WW - 2);   // gw is even -> aligned
                stg[k] = *(const float2*)(
                    xn + ((size_t)(h * CH + cc) * HH + ghc) * WW + gwc);
            }
        }
    };
    auto stageW = [&]() {               // select-zero halo + LDS write
        float* base = &xlds[0][0][0];
        #pragma unroll
        for (int k = 0; k < NSTG; ++k) {
            int idx = tid + k * 512;
            if (idx < XHALF) {
                int cc  = idx / (LROWS * (LCOLS / 2));
                int rem = idx - cc * (LROWS * (LCOLS / 2));
                int r   = rem / (LCOLS / 2);
                int jp  = rem - r * (LCOLS / 2);
                int gh = h0 - PADK + r;
                int gw = w0 - PADK + 2 * jp;
                bool ok = ((unsigned)gh < (unsigned)HH) &
                          ((unsigned)gw < (unsigned)WW);
                float2 v;
                v.x = ok ? stg[k].x : 0.f;
                v.y = ok ? stg[k].y : 0.f;
                *(float2*)(base + 2 * idx) = v;
            }
        }
    };

    float acc[2][4][2];
    #pragma unroll
    for (int a = 0; a < 2; ++a)
        #pragma unroll
        for (int j = 0; j < 4; ++j) {
            acc[a][j][0] = -INFINITY;
            acc[a][j][1] = -INFINITY;
        }

    auto compute = [&](int h) {
        for (int cc = 0; cc < CH; ++cc) {
            const float* wb = &wlds[((h * CH + cc) * 4 + og) * KK * WSTR];
            #pragma unroll
            for (int dy = 0; dy < KK; ++dy) {
                const float* wch = wb + dy * WSTR;
                float4 wa = *(const float4*)(wch);
                float4 wv = *(const float4*)(wch + 4);
                float2 wc2 = *(const float2*)(wch + 8);
                const float w[10] = {wa.x, wa.y, wa.z, wa.w,
                                     wv.x, wv.y, wv.z, wv.w, wc2.x, wc2.y};
                #pragma unroll
                for (int j = 0; j < 4; ++j) {
                    const float* lr = &xlds[cc][rbase + dy + j][2 * l];
                    float2 a = *(const float2*)(lr);
                    float2 b = *(const float2*)(lr + 2);
                    float2 d = *(const float2*)(lr + 4);
                    const float u0 = a.x, u1 = a.y, u2 = b.x,
                                u3 = b.y, u4 = d.x, u5 = d.y;
                    #pragma unroll
                    for (int o2 = 0; o2 < 2; ++o2) {
                        const float* wo = &w[o2 * 5];
                        float t0 = u0 + wo[0], t1 = u1 + wo[1],
                              t2 = u2 + wo[2], t3 = u3 + wo[3],
                              t4 = u4 + wo[4];
                        acc[o2][j][0] = max3f(acc[o2][j][0],
                                              max3f(t0, t1, t2),
                                              fmaxf(t3, t4));
                        float s0 = u1 + wo[0], s1 = u2 + wo[1],
                              s2 = u3 + wo[2], s3 = u4 + wo[3],
                              s4 = u5 + wo[4];
                        acc[o2][j][1] = max3f(acc[o2][j][1],
                                              max3f(s0, s1, s2),
                                              fmaxf(s3, s4));
                    }
                }
            }
        }
    };

    // ---- prologue: half 0 staged (latency unavoidable on first tile) ----
    stageL(0);
    for (int t = tid; t < NW; t += 512) {     // weights -> LDS, as R10
        int dx = t % KK;  int q = t / KK;
        int o2 = q & 1;   q >>= 1;
        int dy = q % KK;  q /= KK;
        int g  = q & 3;   int c = q >> 2;
        int o = g * 2 + o2;
        wlds[((c * 4 + g) * KK + dy) * WSTR + o2 * KK + dx] =
            wf[((o * C_IN + c) * KK + dy) * KK + dx];
    }
    stageW();
    __syncthreads();

    // ---- issue half-1 loads BEFORE compute(0): 25 us of latency cover ----
    stageL(1);
    asm volatile("" ::: "memory");   // pin load issue above the compute
    compute(0);
    __syncthreads();                 // vmcnt drain here is free (loads done)
    stageW();
    __syncthreads();
    compute(1);

    // ---- store: 2 consecutive pixels -> one float2, coalesced ----
    float* onp = out + (size_t)n * (O_OUT * HH * WW);
    const int hB = h0 + rbase;
    const int wcol = w0 + 2 * l;
    #pragma unroll
    for (int o2 = 0; o2 < 2; ++o2) {
        const int o = og * 2 + o2;
        #pragma unroll
        for (int j = 0; j < 4; ++j) {
            float2 rr = make_float2(acc[o2][j][0], acc[o2][j][1]);
            *(float2*)(&onp[((size_t)o * HH + hB + j) * WW + wcol]) = rr;
        }
    }
}

extern "C" void kernel_launch(void* const* d_in, const int* in_sizes, int n_in,
                              void* d_out, int out_size, void* d_ws, size_t ws_size,
                              hipStream_t stream) {
    const float* x   = (const float*)d_in[0];
    const float* wgt = (const float*)d_in[1];
    float* out = (float*)d_out;

    dim3 grid(WW / TW, HH / TH, 4);   // (4, 64, 4) = 1024 blocks x 512 thr
    dim3 block(512);
    dil_kernel<<<grid, block, 0, stream>>>(x, wgt, out);
}

// Round 16
// 65.107 us; speedup vs baseline: 1.1643x; 1.1643x over previous
//
#include <hip/hip_runtime.h>
#include <math.h>
#include <stdint.h>

#define KK 5
#define PADK 2
#define C_IN 8
#define O_OUT 8
#define HH 512
#define WW 512
#define TH 8
#define TW 128
#define CH 4                      // channels per staged half
#define LROWS 12                  // TH + 4
#define LCOLS 136                 // TW + 4 halo, padded (f32 cols)
#define WSTR 12                   // dwords per (c,og,dy) chunk: 10 used
#define NW (O_OUT * C_IN * KK * KK)   // 1600
#define XHALF (CH * LROWS * (LCOLS / 2))   // float2 slots per half = 3264

// Full-rate VOP3 3-input max.
static __device__ __forceinline__ float max3f(float a, float b, float c) {
    float d;
    asm("v_max3_f32 %0, %1, %2, %3" : "=v"(d) : "v"(a), "v"(b), "v"(c));
    return d;
}

__global__ __launch_bounds__(512, 8)
void dil_kernel(const float* __restrict__ x,
                const float* __restrict__ wf,
                float* __restrict__ out) {
    __shared__ __align__(16) float xlds[CH][LROWS][LCOLS];      // 26,112 B
    __shared__ __align__(16) float wlds[C_IN * 4 * KK * WSTR];  //  7,680 B

    const int tid = threadIdx.x;
    const int w0 = blockIdx.x * TW;
    const int h0 = blockIdx.y * TH;
    const int n  = blockIdx.z;
    const float* xn = x + (size_t)n * (C_IN * HH * WW);

    // wave -> (o-pair og, row-quad rq); lane -> 2-pixel column strip
    const int l   = tid & 63;
    const int wid = tid >> 6;
    const int og  = wid & 3;
    const int rbase = (wid >> 2) * 4;

    // ---- SINGLE base pointers; every read below is base + compile-time
    //      constant -> folds into the ds_read 16-bit offset immediate. ----
    const float* xbase = &xlds[0][rbase][2 * l];
    const float* wog   = wlds + og * (KK * WSTR);

    float acc[2][4][2];
    #pragma unroll
    for (int a = 0; a < 2; ++a)
        #pragma unroll
        for (int j = 0; j < 4; ++j) {
            acc[a][j][0] = -INFINITY;
            acc[a][j][1] = -INFINITY;
        }

    for (int h = 0; h < 2; ++h) {
        if (h) __syncthreads();        // all waves done with xlds half 0

        // ---- stage x half (4 channels), zero halo == reference zero pad ----
        for (int idx = tid; idx < XHALF; idx += 512) {
            int cc  = idx / (LROWS * (LCOLS / 2));
            int rem = idx - cc * (LROWS * (LCOLS / 2));
            int r   = rem / (LCOLS / 2);
            int jp  = rem - r * (LCOLS / 2);
            int gh = h0 - PADK + r;
            int gw = w0 - PADK + 2 * jp;
            float v0 = 0.f, v1 = 0.f;
            if ((unsigned)gh < (unsigned)HH) {
                const float* row = xn + ((size_t)(h * CH + cc) * HH + gh) * WW;
                if ((unsigned)gw < (unsigned)WW) v0 = row[gw];
                if ((unsigned)(gw + 1) < (unsigned)WW) v1 = row[gw + 1];
            }
            *(float2*)&xlds[cc][r][2 * jp] = make_float2(v0, v1);
        }
        // ---- stage weights once: layout [c][og][dy][o2*5+dx] ----
        if (h == 0) {
            for (int t = tid; t < NW; t += 512) {
                int dx = t % KK;  int q = t / KK;
                int o2 = q & 1;   q >>= 1;
                int dy = q % KK;  q /= KK;
                int g  = q & 3;   int c = q >> 2;
                int o = g * 2 + o2;
                wlds[((c * 4 + g) * KK + dy) * WSTR + o2 * KK + dx] =
                    wf[((o * C_IN + c) * KK + dy) * KK + dx];
            }
        }
        __syncthreads();

        // one add per half for the weight base; all else immediate offsets
        const float* wh = wog + h * (CH * 4 * KK * WSTR);

        #pragma unroll
        for (int cc = 0; cc < CH; ++cc) {
            #pragma unroll
            for (int dy = 0; dy < KK; ++dy) {
                // weight chunk: compile-time offset from wh
                const float* wch = wh + (cc * 4 * KK + dy) * WSTR;
                float4 wa = *(const float4*)(wch);
                float4 wv = *(const float4*)(wch + 4);
                float2 wc2 = *(const float2*)(wch + 8);
                const float w[10] = {wa.x, wa.y, wa.z, wa.w,
                                     wv.x, wv.y, wv.z, wv.w, wc2.x, wc2.y};
                #pragma unroll
                for (int j = 0; j < 4; ++j) {
                    // row (cc, rbase+dy+j): compile-time offset from xbase;
                    // identical rows across (dy,j) CSE to one load set
                    const float* lr = xbase + cc * (LROWS * LCOLS)
                                            + (dy + j) * LCOLS;
                    float2 A = *(const float2*)(lr);
                    float2 B = *(const float2*)(lr + 2);
                    float2 D = *(const float2*)(lr + 4);
                    const float u0 = A.x, u1 = A.y, u2 = B.x,
                                u3 = B.y, u4 = D.x, u5 = D.y;
                    #pragma unroll
                    for (int o2 = 0; o2 < 2; ++o2) {
                        const float* wo = &w[o2 * 5];
                        float t0 = u0 + wo[0], t1 = u1 + wo[1],
                              t2 = u2 + wo[2], t3 = u3 + wo[3],
                              t4 = u4 + wo[4];
                        acc[o2][j][0] = max3f(acc[o2][j][0],
                                              max3f(t0, t1, t2),
                                              fmaxf(t3, t4));
                        float s0 = u1 + wo[0], s1 = u2 + wo[1],
                              s2 = u3 + wo[2], s3 = u4 + wo[3],
                              s4 = u5 + wo[4];
                        acc[o2][j][1] = max3f(acc[o2][j][1],
                                              max3f(s0, s1, s2),
                                              fmaxf(s3, s4));
                    }
                }
            }
        }
    }

    // ---- store: 2 consecutive pixels -> one float2, coalesced ----
    float* onp = out + (size_t)n * (O_OUT * HH * WW);
    const int hB = h0 + rbase;
    const int wcol = w0 + 2 * l;
    float* obase = &onp[((size_t)(og * 2) * HH + hB) * WW + wcol];
    #pragma unroll
    for (int o2 = 0; o2 < 2; ++o2) {
        #pragma unroll
        for (int j = 0; j < 4; ++j) {
            float2 rr = make_float2(acc[o2][j][0], acc[o2][j][1]);
            *(float2*)(obase + (size_t)o2 * (HH * WW) + j * WW) = rr;
        }
    }
}

extern "C" void kernel_launch(void* const* d_in, const int* in_sizes, int n_in,
                              void* d_out, int out_size, void* d_ws, size_t ws_size,
                              hipStream_t stream) {
    const float* x   = (const float*)d_in[0];
    const float* wgt = (const float*)d_in[1];
    float* out = (float*)d_out;

    dim3 grid(WW / TW, HH / TH, 4);   // (4, 64, 4) = 1024 blocks x 512 thr
    dim3 block(512);
    dil_kernel<<<grid, block, 0, stream>>>(x, wgt, out);
}